// Round 7
// baseline (300.594 us; speedup 1.0000x reference)
//
#include <hip/hip_runtime.h>
#include <stdint.h>

// Problem constants (from reference setup_inputs)
#define M_TOK 8192
#define N_OUT 4096
#define K_IN  4096

// GEMM tiling: 256x256 tile, BK=64, double-buffered LDS (128 KiB), 8 waves 2x4
#define BM 256
#define BN 256
#define BK 64
#define NT (K_IN / BK)            // 64 K-tiles
#define BUF 32768                 // shorts per buffer (64 KiB)
#define SEC 8192                  // shorts per k-slice section (256 rows x 32)

typedef float floatx4 __attribute__((ext_vector_type(4)));
typedef __bf16 bf16x8 __attribute__((ext_vector_type(8)));
typedef unsigned short ushort8_t __attribute__((ext_vector_type(8)));

#define MFMA16 __builtin_amdgcn_mfma_f32_16x16x32_bf16

// ---------- helpers ----------

__device__ __forceinline__ unsigned short f32_to_bf16_rne(float f) {
    union { float f; unsigned int u; } v; v.f = f;
    unsigned int u = v.u;
    u += 0x7FFFu + ((u >> 16) & 1u);   // round-to-nearest-even; inputs have no NaN
    return (unsigned short)(u >> 16);
}

// async global->LDS, 16 bytes per lane. LDS side is wave-uniform base + lane*16.
__device__ __forceinline__ void async_copy16(const void* g, void* l) {
    __builtin_amdgcn_global_load_lds(
        (__attribute__((address_space(1))) void*)(g),
        (__attribute__((address_space(3))) void*)(l),
        16, 0, 0);
}

// ---------- pre-pass: fp32 -> bf16 ----------

__global__ void cvt_f32_bf16_kernel(const float* __restrict__ in,
                                    unsigned short* __restrict__ out, int n8) {
    int i = blockIdx.x * 256 + threadIdx.x;
    if (i >= n8) return;
    const float4* p = (const float4*)in + (size_t)i * 2;
    float4 a = p[0];
    float4 b = p[1];
    ushort8_t o;
    o[0] = f32_to_bf16_rne(a.x); o[1] = f32_to_bf16_rne(a.y);
    o[2] = f32_to_bf16_rne(a.z); o[3] = f32_to_bf16_rne(a.w);
    o[4] = f32_to_bf16_rne(b.x); o[5] = f32_to_bf16_rne(b.y);
    o[6] = f32_to_bf16_rne(b.z); o[7] = f32_to_bf16_rne(b.w);
    *((ushort8_t*)out + i) = o;
}

// ---------- pre-pass: int32 (int8-valued) -> bf16 (exact) ----------

__global__ void cvt_i32_bf16_kernel(const int* __restrict__ in,
                                    unsigned short* __restrict__ out, int n8) {
    int i = blockIdx.x * 256 + threadIdx.x;
    if (i >= n8) return;
    const int4* p = (const int4*)in + (size_t)i * 2;
    int4 a = p[0];
    int4 b = p[1];
    ushort8_t o;
    o[0] = f32_to_bf16_rne((float)a.x); o[1] = f32_to_bf16_rne((float)a.y);
    o[2] = f32_to_bf16_rne((float)a.z); o[3] = f32_to_bf16_rne((float)a.w);
    o[4] = f32_to_bf16_rne((float)b.x); o[5] = f32_to_bf16_rne((float)b.y);
    o[6] = f32_to_bf16_rne((float)b.z); o[7] = f32_to_bf16_rne((float)b.w);
    *((ushort8_t*)out + i) = o;
}

// ---------- GEMM: C[m][n] = sum_k A[m][k]*B[n][k]; C = acc*scale[n]+bias[n] ----------
// ONE-SLOT-AHEAD fragment pipeline (fixes R4/R6's measured DS<->MFMA
// alternation: MfmaUtil 50% + DS busy 50% = pipes serializing). Every MFMA
// phase's ds_reads are issued one full phase (~620 cyc) before their counted
// lgkm wait, so the CU DS queue (~576 cyc/phase-burst) is serviced UNDER the
// MFMA windows. Publish points shifted to {end-P1, end-P3} so even the
// tile-boundary reads (M1(t+1), issued in P4(t)) have a full slot of cover.
//
// Per-slot ledger (per wave; DS in-order; reads 4/8/4/8 per slot):
//  P1: stage As0(t+1) | read A47s0->af2 (4)  | lgkm(4)  -> M1 frags ready |
//      MFMA M1 = af1 x bf1 -> acc[0..3]      | vmcnt(2) drains s1(t) | barrier
//  P2: stage Bs0(t+1) | read A03s1->af1, Bs1->bf2 (8) | lgkm(8) |
//      MFMA M2 = af2 x bf1 -> acc[4..7]
//  P3: stage As1(t+1) | read A47s1->af2 (4)  | lgkm(4) |
//      MFMA M3 = af1 x bf2 -> acc[0..3]      | vmcnt(2) drains s0(t+1) | barrier
//  P4: stage Bs1(t+1) | read A03s0(t+1)->af1, Bs0(t+1)->bf1 (8) | lgkm(8) |
//      MFMA M4 = af2 x bf2 -> acc[4..7]
// vmcnt(2): outstanding = 6 at each drain point (3 stage-pairs in flight);
// drains the 2 oldest pairs, each issued 1-2 slots earlier. Never vmcnt(0)
// in steady state. Register rotation af1/af2/bf1/bf2 has verified disjoint
// lifetimes (same 64 frag VGPRs as R4). Hazard matrix verified: every LDS
// region's last read is lgkm-drained before its reader's next barrier, which
// precedes the overwriting stage by >=2 slots.
//
// LDS: k-slice sections A_s0 | A_s1 | B_s0 | B_s1, 16 KiB each, PAIR-ROW
// swizzle (R3/R4-verified 0 conflicts): pair p = row>>1 (128 B) holds rows
// {2p,2p+1}; chunk (p,c): cg = c ^ (p&7); inverse on the per-lane GLOBAL
// source, linear LDS dest. Each ds_read_b128 covers one contiguous 1024 B
// window exactly once (R5's 32x32 reads lacked this -> 2.5e7 conflicts).

__global__ __launch_bounds__(512, 2)
void gemm_bf16_kernel(const unsigned short* __restrict__ A,
                      const unsigned short* __restrict__ B,
                      const float* __restrict__ scales,
                      const float* __restrict__ bias,
                      float* __restrict__ C) {
    __shared__ __align__(16) unsigned short lds[2 * BUF];   // 128 KiB

    const int tid = threadIdx.x;

    // T1: bijective XCD swizzle (nwg = 512, divisible by 8), bn-fastest.
    const int nwg = (M_TOK / BM) * (N_OUT / BN);   // 32*16 = 512
    const int cpx = nwg / 8;                        // 64
    const int wg  = (blockIdx.x % 8) * cpx + blockIdx.x / 8;
    const int bn  = wg & 15;                        // N_OUT/BN = 16
    const int bm  = wg >> 4;                        // 0..31

    const int lane = tid & 63;
    const int wave = tid >> 6;          // 0..7
    const int wm   = wave >> 2;         // 0..1 -> rows wm*128
    const int wn   = wave & 3;          // 0..3 -> cols wn*64

    // ---- staging addressing (loop-invariant; R3-verified) ----
    const int t8 = tid >> 3;                        // 0..63
    const int cg = (tid & 7) ^ (t8 & 7);            // unswizzled chunk in pair
    const int grow0 = 2 * t8 + (cg >> 2);           // row within 128-row issue
    const int gcol0 = (cg & 3) * 8;                 // shorts within k-slice
    const unsigned short* aP = A + (size_t)(bm * BM + grow0) * K_IN + gcol0;
    const unsigned short* bP = B + (size_t)(bn * BN + grow0) * K_IN + gcol0;

    auto stA = [&](int tt, int s) {
        unsigned short* d = &lds[(tt & 1) * BUF + s * SEC + tid * 8];
        const unsigned short* g = aP + tt * BK + s * 32;
        async_copy16(g, d);
        async_copy16(g + (size_t)128 * K_IN, d + 4096);
    };
    auto stB = [&](int tt, int s) {
        unsigned short* d = &lds[(tt & 1) * BUF + 2 * SEC + s * SEC + tid * 8];
        const unsigned short* g = bP + tt * BK + s * 32;
        async_copy16(g, d);
        async_copy16(g + (size_t)128 * K_IN, d + 4096);
    };

    // ---- fragment read addressing (loop-invariant) ----
    // Frag row R: pair p = R>>1, c = ((R&1)*4 + q) ^ ((R>>1)&7).
    const int r16 = lane & 15;
    const int q   = lane >> 4;                      // 0..3
    const int cr  = (((r16 & 1) << 2) + q) ^ ((r16 >> 1) & 7);
    const int aOff = (wm * 64 + (r16 >> 1)) * 64 + cr * 8;
    const int bOff = 2 * SEC + (wn * 32 + (r16 >> 1)) * 64 + cr * 8;

    floatx4 acc[8][4] = {};
    bf16x8 af1[4], af2[4], bf1[4], bf2[4];

    // ---- prologue: stage tile 0, drain all, publish, read M1(0)'s frags ----
    stA(0, 0); stB(0, 0); stA(0, 1); stB(0, 1);
    asm volatile("s_waitcnt vmcnt(0)" ::: "memory");
    __builtin_amdgcn_s_barrier();
    asm volatile("" ::: "memory");
    {
        const unsigned short* ar = lds + aOff;
        const unsigned short* br = lds + bOff;
#pragma unroll
        for (int i = 0; i < 4; ++i) af1[i] = *(const bf16x8*)(ar + i * 512);
#pragma unroll
        for (int j = 0; j < 4; ++j) bf1[j] = *(const bf16x8*)(br + j * 512);
    }

#pragma unroll 1
    for (int t = 0; t < NT; ++t) {
        const unsigned short* ar  = lds + (t & 1) * BUF + aOff;
        const unsigned short* br  = lds + (t & 1) * BUF + bOff;
        const unsigned short* ar2 = lds + ((t + 1) & 1) * BUF + aOff;
        const unsigned short* br2 = lds + ((t + 1) & 1) * BUF + bOff;
        const bool pf = (t + 1 < NT);

        // ---- P1: stage As0' | read A47s0->af2 | M1 | publish s1(t) ----
        if (pf) stA(t + 1, 0);
#pragma unroll
        for (int i = 0; i < 4; ++i) af2[i] = *(const bf16x8*)(ar + (4 + i) * 512);
        asm volatile("s_waitcnt lgkmcnt(4)" ::: "memory");
        __builtin_amdgcn_sched_barrier(0);
        __builtin_amdgcn_s_setprio(1);
#pragma unroll
        for (int i = 0; i < 4; ++i)
#pragma unroll
            for (int j = 0; j < 4; ++j)
                acc[i][j] = MFMA16(af1[i], bf1[j], acc[i][j], 0, 0, 0);
        __builtin_amdgcn_s_setprio(0);
        if (pf) asm volatile("s_waitcnt vmcnt(2)" ::: "memory");
        else    asm volatile("s_waitcnt vmcnt(0)" ::: "memory");
        __builtin_amdgcn_s_barrier();
        asm volatile("" ::: "memory");

        // ---- P2: stage Bs0' | read A03s1->af1, Bs1->bf2 | M2 ----
        if (pf) stB(t + 1, 0);
#pragma unroll
        for (int i = 0; i < 4; ++i) af1[i] = *(const bf16x8*)(ar + SEC + i * 512);
#pragma unroll
        for (int j = 0; j < 4; ++j) bf2[j] = *(const bf16x8*)(br + SEC + j * 512);
        asm volatile("s_waitcnt lgkmcnt(8)" ::: "memory");
        __builtin_amdgcn_sched_barrier(0);
        __builtin_amdgcn_s_setprio(1);
#pragma unroll
        for (int i = 0; i < 4; ++i)
#pragma unroll
            for (int j = 0; j < 4; ++j)
                acc[4 + i][j] = MFMA16(af2[i], bf1[j], acc[4 + i][j], 0, 0, 0);
        __builtin_amdgcn_s_setprio(0);

        // ---- P3: stage As1' | read A47s1->af2 | M3 | publish s0(t+1) ----
        if (pf) stA(t + 1, 1);
#pragma unroll
        for (int i = 0; i < 4; ++i) af2[i] = *(const bf16x8*)(ar + SEC + (4 + i) * 512);
        asm volatile("s_waitcnt lgkmcnt(4)" ::: "memory");
        __builtin_amdgcn_sched_barrier(0);
        __builtin_amdgcn_s_setprio(1);
#pragma unroll
        for (int i = 0; i < 4; ++i)
#pragma unroll
            for (int j = 0; j < 4; ++j)
                acc[i][j] = MFMA16(af1[i], bf2[j], acc[i][j], 0, 0, 0);
        __builtin_amdgcn_s_setprio(0);
        if (pf) asm volatile("s_waitcnt vmcnt(2)" ::: "memory");
        __builtin_amdgcn_s_barrier();
        asm volatile("" ::: "memory");

        // ---- P4: stage Bs1' | read A03s0(t+1)->af1, Bs0(t+1)->bf1 | M4 ----
        if (pf) {
            stB(t + 1, 1);
#pragma unroll
            for (int i = 0; i < 4; ++i) af1[i] = *(const bf16x8*)(ar2 + i * 512);
#pragma unroll
            for (int j = 0; j < 4; ++j) bf1[j] = *(const bf16x8*)(br2 + j * 512);
            asm volatile("s_waitcnt lgkmcnt(8)" ::: "memory");
        } else {
            asm volatile("s_waitcnt lgkmcnt(0)" ::: "memory");
        }
        __builtin_amdgcn_sched_barrier(0);
        __builtin_amdgcn_s_setprio(1);
#pragma unroll
        for (int i = 0; i < 4; ++i)
#pragma unroll
            for (int j = 0; j < 4; ++j)
                acc[4 + i][j] = MFMA16(af2[i], bf2[j], acc[4 + i][j], 0, 0, 0);
        __builtin_amdgcn_s_setprio(0);
    }

    // ---- epilogue: C/D layout col = lane&15, row = (lane>>4)*4 + reg ----
    const int row0 = bm * BM + wm * 128 + q * 4;
    const int col0 = bn * BN + wn * 64 + r16;
#pragma unroll
    for (int fc = 0; fc < 4; ++fc) {
        const int n  = col0 + fc * 16;
        const float sc = scales[n];
        const float bi = bias[n];
#pragma unroll
        for (int fr = 0; fr < 8; ++fr) {
            const int m = row0 + fr * 16;
#pragma unroll
            for (int r = 0; r < 4; ++r)
                C[(size_t)(m + r) * N_OUT + n] = acc[fr][fc][r] * sc + bi;
        }
    }
}

// ---------- launch ----------

extern "C" void kernel_launch(void* const* d_in, const int* in_sizes, int n_in,
                              void* d_out, int out_size, void* d_ws, size_t ws_size,
                              hipStream_t stream) {
    const float* x      = (const float*)d_in[0];
    const int*   wq     = (const int*)d_in[1];
    const float* scales = (const float*)d_in[2];
    const float* bias   = (const float*)d_in[3];
    float*       out    = (float*)d_out;

    unsigned short* xb = (unsigned short*)d_ws;                       // 64 MiB
    unsigned short* wb = xb + (size_t)M_TOK * K_IN;                   // 32 MiB
    // ws needed: (8192*4096 + 4096*4096) * 2 = 96 MiB

    const int nx8 = (M_TOK * K_IN) / 8;   // 4194304
    const int nw8 = (N_OUT * K_IN) / 8;   // 2097152
    cvt_f32_bf16_kernel<<<nx8 / 256, 256, 0, stream>>>(x, xb, nx8);
    cvt_i32_bf16_kernel<<<nw8 / 256, 256, 0, stream>>>(wq, wb, nw8);

    const int grid = (M_TOK / BM) * (N_OUT / BN);   // 32 * 16 = 512
    gemm_bf16_kernel<<<grid, 512, 0, stream>>>(xb, wb, scales, bias, out);
}